// Round 15
// baseline (514.651 us; speedup 1.0000x reference)
//
#include <hip/hip_runtime.h>
#include <hip/hip_bf16.h>

#define BB 4
#define SS 4096
#define EE 64
#define DD 512
#define KVBLK 32
#define NET 16  // KV tiles per eighth

typedef __attribute__((ext_vector_type(4))) float f32x4;
typedef __attribute__((ext_vector_type(8))) _Float16 f16x8;
typedef unsigned short u16;
typedef unsigned int u32;

__device__ __forceinline__ u16 f2h(float f) {
  _Float16 h = (_Float16)f;
  return __builtin_bit_cast(u16, h);
}
__device__ __forceinline__ float h2f(u16 b) {
  return (float)__builtin_bit_cast(_Float16, b);
}

__device__ __forceinline__ void async16(const void* g, void* l) {
  __builtin_amdgcn_global_load_lds(
      (const __attribute__((address_space(1))) void*)g,
      (__attribute__((address_space(3))) void*)l, 16, 0, 0);
}

// ---------------- K1: q,k projection (fp32 VALU), emit fp16 ----------------
__global__ __launch_bounds__(256) void qk_proj(
    const float* __restrict__ x,
    const float* __restrict__ Wq, const float* __restrict__ bq,
    const float* __restrict__ Wk, const float* __restrict__ bk,
    u16* __restrict__ qb, u16* __restrict__ kb) {
  __shared__ float xs[32][EE];
  const int tid = threadIdx.x;
  const int row0 = blockIdx.x * 32;
  const float* W = blockIdx.y ? Wk : Wq;
  const float* bias = blockIdx.y ? bk : bq;
  u16* dst = blockIdx.y ? kb : qb;

  #pragma unroll
  for (int i = 0; i < 2; ++i) {
    int idx = tid + 256 * i;
    int r = idx >> 4, c = (idx & 15) * 4;
    *(float4*)&xs[r][c] = *(const float4*)&x[(size_t)(row0 + r) * EE + c];
  }
  __syncthreads();

  const int col = (tid & 127) * 4;
  const int rg = (tid >> 7) * 16;
  float acc[16][4];
  #pragma unroll
  for (int r = 0; r < 16; ++r)
    #pragma unroll
    for (int j = 0; j < 4; ++j) acc[r][j] = 0.f;

  for (int k = 0; k < EE; k += 4) {
    float4 wr[4];
    #pragma unroll
    for (int j = 0; j < 4; ++j) wr[j] = *(const float4*)&W[(size_t)(k + j) * DD + col];
    #pragma unroll
    for (int r = 0; r < 16; ++r) {
      float4 xv = *(const float4*)&xs[rg + r][k];
      acc[r][0] += xv.x * wr[0].x + xv.y * wr[1].x + xv.z * wr[2].x + xv.w * wr[3].x;
      acc[r][1] += xv.x * wr[0].y + xv.y * wr[1].y + xv.z * wr[2].y + xv.w * wr[3].y;
      acc[r][2] += xv.x * wr[0].z + xv.y * wr[1].z + xv.z * wr[2].z + xv.w * wr[3].z;
      acc[r][3] += xv.x * wr[0].w + xv.y * wr[1].w + xv.z * wr[2].w + xv.w * wr[3].w;
    }
  }

  const float4 b4 = *(const float4*)&bias[col];
  #pragma unroll
  for (int r = 0; r < 16; ++r) {
    ushort4 o;
    o.x = f2h(acc[r][0] + b4.x);
    o.y = f2h(acc[r][1] + b4.y);
    o.z = f2h(acc[r][2] + b4.z);
    o.w = f2h(acc[r][3] + b4.w);
    *(ushort4*)&dst[(size_t)(row0 + rg + r) * DD + col] = o;
  }
}

// ---------------- K1b: Wf = Wv @ Wo (64x64), bf = bv @ Wo — PARALLEL ----------------
__global__ __launch_bounds__(256) void wfuse(
    const float* __restrict__ Wv, const float* __restrict__ bv,
    const float* __restrict__ Wo, float* __restrict__ Wf, float* __restrict__ bf) {
  __shared__ float red[4][64];
  const int tid = threadIdx.x;
  const int d = tid & 63, kq = tid >> 6;
  const int e = blockIdx.x;
  const float* src = (e < 64) ? &Wv[(size_t)e * DD] : bv;
  float a = 0.f;
  #pragma unroll 4
  for (int k = kq * 128; k < (kq + 1) * 128; ++k)
    a += src[k] * Wo[(size_t)k * EE + d];
  red[kq][d] = a;
  __syncthreads();
  if (tid < 64) {
    float s = (red[0][tid] + red[1][tid]) + (red[2][tid] + red[3][tid]);
    if (e < 64) Wf[e * EE + tid] = s;
    else bf[tid] = s;
  }
}

// ---------------- K1c: VWt[b][d][s] = (x @ Wf + bf)^T, fp16 ----------------
__global__ __launch_bounds__(256) void vw_proj(
    const float* __restrict__ x, const float* __restrict__ Wf,
    const float* __restrict__ bf, u16* __restrict__ vwt) {
  __shared__ float xs[64][EE];
  __shared__ float wfs[EE][64];
  __shared__ float bfs[64];
  const int tid = threadIdx.x;
  const int b = blockIdx.x & 3;
  const int s0 = (blockIdx.x >> 2) * 64;

  #pragma unroll
  for (int i = 0; i < 4; ++i) {
    int idx = tid + 256 * i;
    int r = idx >> 4, c = (idx & 15) * 4;
    *(float4*)&xs[r][c] = *(const float4*)&x[((size_t)b * SS + s0 + r) * EE + c];
    *(float4*)&wfs[r][c] = *(const float4*)&Wf[(size_t)r * 64 + c];
  }
  if (tid < 64) bfs[tid] = bf[tid];
  __syncthreads();

  const int d = tid & 63, sg = tid >> 6;
  float acc[16];
  #pragma unroll
  for (int i = 0; i < 16; ++i) acc[i] = bfs[d];
  for (int e = 0; e < EE; ++e) {
    float wv = wfs[e][d];
    #pragma unroll
    for (int i = 0; i < 16; ++i) acc[i] += xs[sg * 16 + i][e] * wv;
  }
  u16* dst = vwt + ((size_t)b * 64 + d) * SS + s0 + sg * 16;
  union { uint4 u[2]; u16 hh[16]; } o;
  #pragma unroll
  for (int i = 0; i < 16; ++i) o.hh[i] = f2h(acc[i]);
  *(uint4*)dst = o.u[0];
  *(uint4*)(dst + 8) = o.u[1];
}

// ---------------- K1d: mask block-sparsity scan ----------------
__global__ __launch_bounds__(256) void mask_scan(
    const float* __restrict__ mask, unsigned char* __restrict__ flags) {
  __shared__ int fl[32];
  const int tid = threadIdx.x;
  const int bid = blockIdx.x;
  const int tq = bid & 3;          // t-quarter (1024 floats)
  const int qb = (bid >> 2) & 31;  // q-block of 128 rows
  const int b = bid >> 7;
  if (tid < 32) fl[tid] = 0;
  __syncthreads();
  const size_t rbase = ((size_t)(b * SS + qb * 128)) * SS + tq * 1024 + tid * 4;
  #pragma unroll 1
  for (int r = 0; r < 128; ++r) {
    float4 v = *(const float4*)&mask[rbase + (size_t)r * SS];
    int nz = (v.x != 0.f) | (v.y != 0.f) | (v.z != 0.f) | (v.w != 0.f);
    nz |= __shfl_xor(nz, 1);
    nz |= __shfl_xor(nz, 2);
    nz |= __shfl_xor(nz, 4);
    if (nz && ((tid & 7) == 0)) atomicOr(&fl[tid >> 3], 1);
  }
  __syncthreads();
  if (tid < 32)
    flags[((size_t)(b * 32 + qb)) * 128 + tq * 32 + tid] = (unsigned char)fl[tid];
}

// ---------------- K2: flash attention v12 (2x K-reuse: 32 q-rows/warp) ----------------
// 512 blocks x 512 thr (8 warps x 32q = 256 q-rows), 2 blocks/CU.
// bid&31 = (b, kv-eighth); XCD x handles eighth x only -> K L2-resident.
// Each K fragment read from LDS feeds 4 MFMAs (2 q-subtiles x 2 t-halves):
// halves LDS traffic vs v11. Single-buffered Ks staged post-B1 (round-10 timing).
// LDS: Ks[32][512] 32K | Ps[8][32][36] 18K = 50 KiB dynamic
__global__ __launch_bounds__(512, 4) void attn_fwd(
    const u16* __restrict__ qbuf, const u16* __restrict__ kbuf,
    const u16* __restrict__ vwt, const float* __restrict__ mask,
    const unsigned char* __restrict__ flags,
    float* __restrict__ opart, float* __restrict__ stats) {
  extern __shared__ char smem[];
  u16* PsS = (u16*)(smem + 32768);

  const int tid = threadIdx.x;
  const int lane = tid & 63;
  const int w = tid >> 6;  // 0..7
  const int lrow = lane & 15, lhi = lane >> 4;

  const int bid = blockIdx.x;
  const int grp = bid & 31;
  const int b = grp >> 3, e8 = grp & 7;
  const int qb = bid >> 5;          // 0..15 (256-row q-blocks)
  const int q0 = qb * 256;
  const int tbase = e8 * (SS / 8);

  const int qrow0 = q0 + w * 32 + lrow;
  const int qrow1 = qrow0 + 16;

  // ---- Q -> registers: two q-subtiles ----
  f16x8 qreg0[16], qreg1[16];
  {
    const u16* qg0 = qbuf + ((size_t)b * SS + qrow0) * DD + lhi * 8;
    const u16* qg1 = qg0 + (size_t)16 * DD;
    #pragma unroll
    for (int kk = 0; kk < 16; ++kk) {
      qreg0[kk] = *(const f16x8*)(qg0 + kk * 32);
      qreg1[kk] = *(const f16x8*)(qg1 + kk * 32);
    }
  }

  auto stage_k = [&](int t0n) {
    const char* kg = (const char*)(kbuf + ((size_t)b * SS + t0n) * DD);
    #pragma unroll
    for (int rr = 0; rr < 4; ++rr) {
      int row = w * 4 + rr;
      async16(kg + (size_t)row * 1024 + ((lane * 16) ^ ((row & 7) << 4)),
              (char*)smem + row * 1024);
    }
  };

  float m0 = -3.0e38f, l0 = 0.f, m1 = -3.0e38f, l1 = 0.f;
  f32x4 acc0[4], acc1[4];
  #pragma unroll
  for (int f = 0; f < 4; ++f) {
    acc0[f] = (f32x4){0.f, 0.f, 0.f, 0.f};
    acc1[f] = (f32x4){0.f, 0.f, 0.f, 0.f};
  }

  const u16* vwb = vwt + (size_t)b * 64 * SS;
  const size_t mrow0 = ((size_t)b * SS + qrow0) * SS;
  const size_t mrow1 = mrow0 + (size_t)16 * SS;
  const unsigned char* flg = flags + ((size_t)(b * 32 + qb * 2)) * 128 + e8 * 16;

  // ---- prologue: K(0) ----
  stage_k(tbase);
  asm volatile("s_waitcnt vmcnt(0)" ::: "memory");
  __syncthreads();

  u16* PsW = PsS + w * 1152;  // warp-private [32][36]
  const int kswz = (lrow & 7) << 4;

  #pragma unroll 1
  for (int it = 0; it < NET; ++it) {
    const int t0 = tbase + it * KVBLK;

    // --- QK^T swapped: 4 chains (2 q-subtiles x 2 t-halves) ---
    f32x4 s00 = (f32x4){0.f, 0.f, 0.f, 0.f};
    f32x4 s01 = (f32x4){0.f, 0.f, 0.f, 0.f};
    f32x4 s10 = (f32x4){0.f, 0.f, 0.f, 0.f};
    f32x4 s11 = (f32x4){0.f, 0.f, 0.f, 0.f};
    {
      const char* kp0 = (const char*)smem + lrow * 1024;
      const char* kp1 = kp0 + 16384;
      __builtin_amdgcn_s_setprio(1);
      #pragma unroll
      for (int kk = 0; kk < 16; ++kk) {
        int off = kk * 64 + lhi * 16;
        f16x8 k0 = *(const f16x8*)(kp0 + (off ^ kswz));
        f16x8 k1 = *(const f16x8*)(kp1 + (off ^ kswz));
        s00 = __builtin_amdgcn_mfma_f32_16x16x32_f16(k0, qreg0[kk], s00, 0, 0, 0);
        s01 = __builtin_amdgcn_mfma_f32_16x16x32_f16(k1, qreg0[kk], s01, 0, 0, 0);
        s10 = __builtin_amdgcn_mfma_f32_16x16x32_f16(k0, qreg1[kk], s10, 0, 0, 0);
        s11 = __builtin_amdgcn_mfma_f32_16x16x32_f16(k1, qreg1[kk], s11, 0, 0, 0);
      }
      __builtin_amdgcn_s_setprio(0);
    }
    __syncthreads();  // B1: all warps done reading Ks

    // stage next K tile (lands during softmax+PV)
    if (it + 1 < NET) stage_k(t0 + KVBLK);

    // --- mask add (block-sparse gated; flag covers both 128-row halves) ---
    if (flg[it] | flg[128 + it]) {
      const float4 a0 = *(const float4*)&mask[mrow0 + t0 + lhi * 4];
      const float4 b0 = *(const float4*)&mask[mrow0 + t0 + 16 + lhi * 4];
      const float4 a1 = *(const float4*)&mask[mrow1 + t0 + lhi * 4];
      const float4 b1 = *(const float4*)&mask[mrow1 + t0 + 16 + lhi * 4];
      s00[0] += a0.x; s00[1] += a0.y; s00[2] += a0.z; s00[3] += a0.w;
      s01[0] += b0.x; s01[1] += b0.y; s01[2] += b0.z; s01[3] += b0.w;
      s10[0] += a1.x; s10[1] += a1.y; s10[2] += a1.z; s10[3] += a1.w;
      s11[0] += b1.x; s11[1] += b1.y; s11[2] += b1.z; s11[3] += b1.w;
    }

    // --- in-warp softmax, both subtiles ---
    float px0 = fmaxf(fmaxf(fmaxf(s00[0], s00[1]), fmaxf(s00[2], s00[3])),
                      fmaxf(fmaxf(s01[0], s01[1]), fmaxf(s01[2], s01[3])));
    float px1 = fmaxf(fmaxf(fmaxf(s10[0], s10[1]), fmaxf(s10[2], s10[3])),
                      fmaxf(fmaxf(s11[0], s11[1]), fmaxf(s11[2], s11[3])));
    px0 = fmaxf(px0, __shfl_xor(px0, 16));
    px0 = fmaxf(px0, __shfl_xor(px0, 32));
    px1 = fmaxf(px1, __shfl_xor(px1, 16));
    px1 = fmaxf(px1, __shfl_xor(px1, 32));

    if (__any(fmaxf(px0 - m0, px1 - m1) > 8.0f)) {  // defer-max (T13)
      float mn0 = fmaxf(m0, px0), mn1 = fmaxf(m1, px1);
      float al0 = __expf(m0 - mn0), al1 = __expf(m1 - mn1);
      m0 = mn0; m1 = mn1;
      l0 *= al0; l1 *= al1;
      float av0[4], av1[4];
      #pragma unroll
      for (int r = 0; r < 4; ++r) {
        av0[r] = __shfl(al0, lhi * 4 + r);
        av1[r] = __shfl(al1, lhi * 4 + r);
      }
      #pragma unroll
      for (int f = 0; f < 4; ++f)
        #pragma unroll
        for (int r = 0; r < 4; ++r) {
          acc0[f][r] *= av0[r];
          acc1[f][r] *= av1[r];
        }
    }

    float p0[8], p1[8];
    #pragma unroll
    for (int r = 0; r < 4; ++r) {
      p0[r] = __expf(s00[r] - m0);
      p0[4 + r] = __expf(s01[r] - m0);
      p1[r] = __expf(s10[r] - m1);
      p1[4 + r] = __expf(s11[r] - m1);
    }
    float ps0 = ((p0[0] + p0[1]) + (p0[2] + p0[3])) + ((p0[4] + p0[5]) + (p0[6] + p0[7]));
    float ps1 = ((p1[0] + p1[1]) + (p1[2] + p1[3])) + ((p1[4] + p1[5]) + (p1[6] + p1[7]));
    ps0 += __shfl_xor(ps0, 16);
    ps0 += __shfl_xor(ps0, 32);
    ps1 += __shfl_xor(ps1, 16);
    ps1 += __shfl_xor(ps1, 32);
    l0 += ps0;
    l1 += ps1;

    // --- VW fragments (L2 reads; shared by both subtiles) ---
    uint4 vwf[4];
    #pragma unroll
    for (int f = 0; f < 4; ++f)
      vwf[f] = *(const uint4*)(vwb + ((size_t)(lrow + 16 * f)) * SS + t0 + lhi * 8);

    // --- P -> warp-private LDS roundtrip ---
    {
      uint2 q0w, q1w, q2w, q3w;
      q0w.x = (u32)f2h(p0[0]) | ((u32)f2h(p0[1]) << 16);
      q0w.y = (u32)f2h(p0[2]) | ((u32)f2h(p0[3]) << 16);
      q1w.x = (u32)f2h(p0[4]) | ((u32)f2h(p0[5]) << 16);
      q1w.y = (u32)f2h(p0[6]) | ((u32)f2h(p0[7]) << 16);
      q2w.x = (u32)f2h(p1[0]) | ((u32)f2h(p1[1]) << 16);
      q2w.y = (u32)f2h(p1[2]) | ((u32)f2h(p1[3]) << 16);
      q3w.x = (u32)f2h(p1[4]) | ((u32)f2h(p1[5]) << 16);
      q3w.y = (u32)f2h(p1[6]) | ((u32)f2h(p1[7]) << 16);
      *(uint2*)&PsW[lrow * 36 + lhi * 4] = q0w;
      *(uint2*)&PsW[lrow * 36 + 16 + lhi * 4] = q1w;
      *(uint2*)&PsW[(16 + lrow) * 36 + lhi * 4] = q2w;
      *(uint2*)&PsW[(16 + lrow) * 36 + 16 + lhi * 4] = q3w;
    }
    f16x8 pa0 = *(const f16x8*)&PsW[lrow * 36 + lhi * 8];
    f16x8 pa1 = *(const f16x8*)&PsW[(16 + lrow) * 36 + lhi * 8];

    // --- PV: both subtiles vs shared VW (8 MFMA) ---
    #pragma unroll
    for (int f = 0; f < 4; ++f) {
      f16x8 bfr = __builtin_bit_cast(f16x8, vwf[f]);
      acc0[f] = __builtin_amdgcn_mfma_f32_16x16x32_f16(pa0, bfr, acc0[f], 0, 0, 0);
      acc1[f] = __builtin_amdgcn_mfma_f32_16x16x32_f16(pa1, bfr, acc1[f], 0, 0, 0);
    }

    // --- tile end: K staged + all reads done ---
    asm volatile("s_waitcnt vmcnt(0)" ::: "memory");
    __syncthreads();
  }

  // ---- epilogue: normalized partials (fp32) + (m, l) stats ----
  if (lhi == 0) {
    float2* st = (float2*)stats;
    st[(size_t)e8 * (BB * SS) + (size_t)b * SS + qrow0] = make_float2(m0, l0);
    st[(size_t)e8 * (BB * SS) + (size_t)b * SS + qrow1] = make_float2(m1, l1);
  }
  float rl0[4], rl1[4];
  #pragma unroll
  for (int r = 0; r < 4; ++r) {
    rl0[r] = 1.0f / __shfl(l0, lhi * 4 + r);
    rl1[r] = 1.0f / __shfl(l1, lhi * 4 + r);
  }
  #pragma unroll
  for (int r = 0; r < 4; ++r) {
    size_t base0 = ((size_t)e8 * (BB * SS) + (size_t)b * SS +
                    (size_t)(q0 + w * 32 + lhi * 4 + r)) * 64 + (size_t)lrow;
    size_t base1 = base0 + (size_t)16 * 64;
    #pragma unroll
    for (int f = 0; f < 4; ++f) {
      opart[base0 + f * 16] = acc0[f][r] * rl0[r];
      opart[base1 + f * 16] = acc1[f][r] * rl1[r];
    }
  }
}

// ---------------- K3: merge 8 KV-eighths, add bo ----------------
__global__ __launch_bounds__(256) void merge8(
    const float* __restrict__ opart, const float* __restrict__ stats,
    const float* __restrict__ bo, float* __restrict__ out) {
  const int gid = blockIdx.x * 256 + threadIdx.x;
  const int row = gid >> 3;
  const int c8 = (gid & 7) * 8;
  const float2* st = (const float2*)stats;
  float2 sq[8];
  #pragma unroll
  for (int q = 0; q < 8; ++q) sq[q] = st[(size_t)q * (BB * SS) + row];
  float M = sq[0].x;
  #pragma unroll
  for (int q = 1; q < 8; ++q) M = fmaxf(M, sq[q].x);
  float wv[8], Ssum = 0.f;
  #pragma unroll
  for (int q = 0; q < 8; ++q) {
    wv[q] = __expf(sq[q].x - M) * sq[q].y;
    Ssum += wv[q];
  }
  const float inv = 0.35355339059327373f / Ssum;
  #pragma unroll
  for (int q = 0; q < 8; ++q) wv[q] *= inv;

  float o[8];
  #pragma unroll
  for (int j = 0; j < 8; ++j) o[j] = bo[c8 + j];
  #pragma unroll
  for (int q = 0; q < 8; ++q) {
    const float* op = opart + ((size_t)q * (BB * SS) + row) * 64 + c8;
    float4 a = *(const float4*)op;
    float4 bq4 = *(const float4*)(op + 4);
    o[0] += wv[q] * a.x; o[1] += wv[q] * a.y; o[2] += wv[q] * a.z; o[3] += wv[q] * a.w;
    o[4] += wv[q] * bq4.x; o[5] += wv[q] * bq4.y; o[6] += wv[q] * bq4.z; o[7] += wv[q] * bq4.w;
  }
  float* dst = out + (size_t)row * EE + c8;
  *(float4*)dst = make_float4(o[0], o[1], o[2], o[3]);
  *(float4*)(dst + 4) = make_float4(o[4], o[5], o[6], o[7]);
}

extern "C" void kernel_launch(void* const* d_in, const int* in_sizes, int n_in,
                              void* d_out, int out_size, void* d_ws, size_t ws_size,
                              hipStream_t stream) {
  const float* x = (const float*)d_in[0];
  const float* mask = (const float*)d_in[1];
  const float* Wq = (const float*)d_in[2];
  const float* bq = (const float*)d_in[3];
  const float* Wk = (const float*)d_in[4];
  const float* bk = (const float*)d_in[5];
  const float* Wv = (const float*)d_in[6];
  const float* bv = (const float*)d_in[7];
  const float* Wo = (const float*)d_in[8];
  const float* bo = (const float*)d_in[9];
  float* out = (float*)d_out;

  const size_t N = (size_t)BB * SS * DD;
  u16* qb = (u16*)d_ws;
  u16* kb = qb + N;
  u16* vwt = kb + N;                          // BB*64*SS u16
  float* Wf = (float*)(vwt + (size_t)BB * 64 * SS);
  float* bf = Wf + 64 * 64;
  float* opart = bf + 64;                     // 8 * BB*SS*64 f32
  float* st = opart + (size_t)8 * BB * SS * 64;  // 8 * BB*SS float2
  unsigned char* flags = (unsigned char*)(st + (size_t)16 * BB * SS);  // 16 KB

  qk_proj<<<dim3(BB * SS / 32, 2), 256, 0, stream>>>(x, Wq, bq, Wk, bk, qb, kb);
  wfuse<<<65, 256, 0, stream>>>(Wv, bv, Wo, Wf, bf);
  vw_proj<<<BB * SS / 64, 256, 0, stream>>>(x, Wf, bf, vwt);
  mask_scan<<<512, 256, 0, stream>>>(mask, flags);
  attn_fwd<<<512, 512, 51200, stream>>>(qb, kb, vwt, mask, flags, opart, st);
  merge8<<<BB * SS * 8 / 256, 256, 0, stream>>>(opart, st, bo, out);
}

// Round 16
// 216.480 us; speedup vs baseline: 2.3774x; 2.3774x over previous
//
#include <hip/hip_runtime.h>
#include <hip/hip_bf16.h>

#define BB 4
#define SS 4096
#define EE 64
#define DD 512
#define KVBLK 32
#define NQT 32  // KV tiles per quarter

typedef __attribute__((ext_vector_type(4))) float f32x4;
typedef __attribute__((ext_vector_type(8))) _Float16 f16x8;
typedef unsigned short u16;
typedef unsigned int u32;

__device__ __forceinline__ u16 f2h(float f) {
  _Float16 h = (_Float16)f;
  return __builtin_bit_cast(u16, h);
}
__device__ __forceinline__ float h2f(u16 b) {
  return (float)__builtin_bit_cast(_Float16, b);
}

__device__ __forceinline__ void async16(const void* g, void* l) {
  __builtin_amdgcn_global_load_lds(
      (const __attribute__((address_space(1))) void*)g,
      (__attribute__((address_space(3))) void*)l, 16, 0, 0);
}

// ---------------- K1a: G = Wq @ Wk^T (64x64), g2 = Wk @ bq ----------------
// 65 blocks: e<64 -> G[e][*]; e==64 -> g2.
__global__ __launch_bounds__(256) void gfuse(
    const float* __restrict__ Wq, const float* __restrict__ bq,
    const float* __restrict__ Wk, float* __restrict__ G, float* __restrict__ g2) {
  __shared__ float red[4][64];
  const int tid = threadIdx.x;
  const int f = tid & 63, kq = tid >> 6;
  const int e = blockIdx.x;
  const float* src = (e < 64) ? &Wq[(size_t)e * DD] : bq;
  float a = 0.f;
  #pragma unroll 4
  for (int k = kq * 128; k < (kq + 1) * 128; ++k)
    a += src[k] * Wk[(size_t)f * DD + k];
  red[kq][f] = a;
  __syncthreads();
  if (tid < 64) {
    float s = (red[0][tid] + red[1][tid]) + (red[2][tid] + red[3][tid]);
    if (e < 64) G[e * 64 + tid] = s;
    else g2[tid] = s;
  }
}

// ---------------- K1b: Wf = Wv @ Wo (64x64), bf = bv @ Wo ----------------
__global__ __launch_bounds__(256) void wfuse(
    const float* __restrict__ Wv, const float* __restrict__ bv,
    const float* __restrict__ Wo, float* __restrict__ Wf, float* __restrict__ bf) {
  __shared__ float red[4][64];
  const int tid = threadIdx.x;
  const int d = tid & 63, kq = tid >> 6;
  const int e = blockIdx.x;
  const float* src = (e < 64) ? &Wv[(size_t)e * DD] : bv;
  float a = 0.f;
  #pragma unroll 4
  for (int k = kq * 128; k < (kq + 1) * 128; ++k)
    a += src[k] * Wo[(size_t)k * EE + d];
  red[kq][d] = a;
  __syncthreads();
  if (tid < 64) {
    float s = (red[0][tid] + red[1][tid]) + (red[2][tid] + red[3][tid]);
    if (e < 64) Wf[e * EE + tid] = s;
    else bf[tid] = s;
  }
}

// ---------------- K1c: u = x@G (fp16), c = x@g2 (fp32), xh = fp16(x) ----------------
__global__ __launch_bounds__(256) void uc_proj(
    const float* __restrict__ x, const float* __restrict__ G,
    const float* __restrict__ g2, u16* __restrict__ ubuf,
    u16* __restrict__ xh, float* __restrict__ cbuf) {
  __shared__ float xs[64][EE];
  __shared__ float gs[EE][64];
  __shared__ float g2s[64];
  const int tid = threadIdx.x;
  const int b = blockIdx.x & 3;
  const int s0 = (blockIdx.x >> 2) * 64;

  #pragma unroll
  for (int i = 0; i < 4; ++i) {
    int idx = tid + 256 * i;
    int r = idx >> 4, c = (idx & 15) * 4;
    *(float4*)&xs[r][c] = *(const float4*)&x[((size_t)b * SS + s0 + r) * EE + c];
    *(float4*)&gs[r][c] = *(const float4*)&G[(size_t)r * 64 + c];
  }
  if (tid < 64) g2s[tid] = g2[tid];
  __syncthreads();

  const int d = tid & 63, sg = tid >> 6;
  float acc[16];
  #pragma unroll
  for (int i = 0; i < 16; ++i) acc[i] = 0.f;
  for (int e = 0; e < EE; ++e) {
    float gv = gs[e][d];
    #pragma unroll
    for (int i = 0; i < 16; ++i) acc[i] += xs[sg * 16 + i][e] * gv;
  }
  #pragma unroll
  for (int i = 0; i < 16; ++i)
    ubuf[((size_t)b * SS + s0 + sg * 16 + i) * 64 + d] = f2h(acc[i]);

  if (tid < 64) {
    float cc = 0.f;
    #pragma unroll 8
    for (int e = 0; e < EE; ++e) cc += xs[tid][e] * g2s[e];
    cbuf[(size_t)b * SS + s0 + tid] = cc;
  }
  #pragma unroll
  for (int i = 0; i < 16; ++i) {
    int idx = tid + 256 * i;
    int r = idx >> 6, dd = idx & 63;
    xh[((size_t)b * SS + s0 + r) * 64 + dd] = f2h(xs[r][dd]);
  }
}

// ---------------- K1d: VWt[b][d][s] = (x @ Wf + bf)^T, fp16 ----------------
__global__ __launch_bounds__(256) void vw_proj(
    const float* __restrict__ x, const float* __restrict__ Wf,
    const float* __restrict__ bf, u16* __restrict__ vwt) {
  __shared__ float xs[64][EE];
  __shared__ float wfs[EE][64];
  __shared__ float bfs[64];
  const int tid = threadIdx.x;
  const int b = blockIdx.x & 3;
  const int s0 = (blockIdx.x >> 2) * 64;

  #pragma unroll
  for (int i = 0; i < 4; ++i) {
    int idx = tid + 256 * i;
    int r = idx >> 4, c = (idx & 15) * 4;
    *(float4*)&xs[r][c] = *(const float4*)&x[((size_t)b * SS + s0 + r) * EE + c];
    *(float4*)&wfs[r][c] = *(const float4*)&Wf[(size_t)r * 64 + c];
  }
  if (tid < 64) bfs[tid] = bf[tid];
  __syncthreads();

  const int d = tid & 63, sg = tid >> 6;
  float acc[16];
  #pragma unroll
  for (int i = 0; i < 16; ++i) acc[i] = bfs[d];
  for (int e = 0; e < EE; ++e) {
    float wv = wfs[e][d];
    #pragma unroll
    for (int i = 0; i < 16; ++i) acc[i] += xs[sg * 16 + i][e] * wv;
  }
  u16* dst = vwt + ((size_t)b * 64 + d) * SS + s0 + sg * 16;
  union { uint4 u[2]; u16 hh[16]; } o;
  #pragma unroll
  for (int i = 0; i < 16; ++i) o.hh[i] = f2h(acc[i]);
  *(uint4*)dst = o.u[0];
  *(uint4*)(dst + 8) = o.u[1];
}

// ---------------- K1e: mask block-sparsity scan ----------------
__global__ __launch_bounds__(256) void mask_scan(
    const float* __restrict__ mask, unsigned char* __restrict__ flags) {
  __shared__ int fl[32];
  const int tid = threadIdx.x;
  const int bid = blockIdx.x;
  const int tq = bid & 3;          // t-quarter (1024 floats)
  const int qb = (bid >> 2) & 31;  // q-block of 128 rows
  const int b = bid >> 7;
  if (tid < 32) fl[tid] = 0;
  __syncthreads();
  const size_t rbase = ((size_t)(b * SS + qb * 128)) * SS + tq * 1024 + tid * 4;
  #pragma unroll 1
  for (int r = 0; r < 128; ++r) {
    float4 v = *(const float4*)&mask[rbase + (size_t)r * SS];
    int nz = (v.x != 0.f) | (v.y != 0.f) | (v.z != 0.f) | (v.w != 0.f);
    nz |= __shfl_xor(nz, 1);
    nz |= __shfl_xor(nz, 2);
    nz |= __shfl_xor(nz, 4);
    if (nz && ((tid & 7) == 0)) atomicOr(&fl[tid >> 3], 1);
  }
  __syncthreads();
  if (tid < 32)
    flags[((size_t)(b * 32 + qb)) * 128 + tq * 32 + tid] = (unsigned char)fl[tid];
}

// ---------------- K2: flash attention v13 (algebraic D=64 QK) ----------------
// scores = u_i . x_j + c_j (+ mask); row-consts cancel in softmax.
// 512 blocks x 512 thr (8 warps x 16q = 128 q-rows), 2 blocks/CU.
// K-tile = x rows (4KB!), dbuf async16; u in 8 VGPRs; warp-private softmax;
// PV vs fused VW (d=64). LDS: Ks[2][32][64] 8K | Ps[8][16][36] 9K = 17 KiB.
__global__ __launch_bounds__(512, 4) void attn_fwd(
    const u16* __restrict__ ubuf, const u16* __restrict__ xh,
    const u16* __restrict__ vwt, const float* __restrict__ cbuf,
    const float* __restrict__ mask, const unsigned char* __restrict__ flags,
    float* __restrict__ opart, float* __restrict__ stats) {
  extern __shared__ char smem[];
  u16* PsS = (u16*)(smem + 8192);

  const int tid = threadIdx.x;
  const int lane = tid & 63;
  const int w = tid >> 6;  // 0..7
  const int lrow = lane & 15, lhi = lane >> 4;

  const int bid = blockIdx.x;
  const int grp = bid & 15;
  const int b = grp >> 2, qt = grp & 3;
  const int qb = bid >> 4;
  const int q0 = qb * 128;
  const int tbase = qt * (SS / 4);

  const int qrow = q0 + w * 16 + lrow;

  // ---- u -> registers (B-operand frags, D=64 -> 2 kk steps) ----
  f16x8 qreg[2];
  {
    const u16* qg = ubuf + ((size_t)b * SS + qrow) * 64 + lhi * 8;
    qreg[0] = *(const f16x8*)(qg);
    qreg[1] = *(const f16x8*)(qg + 32);
  }

  // stage a 32x64 fp16 x-tile (4KB): warps 0..3 issue one async16 each.
  auto stage_k = [&](int t0n, int buf) {
    if (w < 4) {
      const char* kg = (const char*)(xh + ((size_t)b * SS + t0n) * 64) + w * 1024;
      int r8 = lane >> 3;  // row within this warp's 8-row group
      int ch = lane & 7;
      async16(kg + r8 * 128 + ((ch * 16) ^ (r8 << 4)),
              (char*)smem + buf * 4096 + w * 1024);
    }
  };

  float m_reg = -3.0e38f, l_reg = 0.f;
  f32x4 acc[4];
  #pragma unroll
  for (int f = 0; f < 4; ++f) acc[f] = (f32x4){0.f, 0.f, 0.f, 0.f};

  const u16* vwb = vwt + (size_t)b * 64 * SS;
  const float* cb = cbuf + (size_t)b * SS;
  const size_t mrow_base = ((size_t)b * SS + qrow) * SS;
  const unsigned char* flg = flags + ((size_t)(b * 32 + qb)) * 128 + qt * 32;

  // ---- prologue: K(0) -> buf0 ----
  stage_k(tbase, 0);
  asm volatile("s_waitcnt vmcnt(0)" ::: "memory");
  __syncthreads();

  u16* PsW = PsS + w * 576;  // warp-private [16][36]
  const int kswz = (lrow & 7) << 4;

  #pragma unroll 1
  for (int it = 0; it < NQT; ++it) {
    const int buf = it & 1;
    const int t0 = tbase + it * KVBLK;

    // --- stage NEXT x-tile (full-tile cover) ---
    if (it + 1 < NQT) stage_k(t0 + KVBLK, buf ^ 1);

    // --- QK^T swapped over D=64 (2 kk x 2 t-halves) ---
    f32x4 s0 = (f32x4){0.f, 0.f, 0.f, 0.f};
    f32x4 s1 = (f32x4){0.f, 0.f, 0.f, 0.f};
    {
      const char* kp0 = (const char*)smem + buf * 4096 + lrow * 128;
      const char* kp1 = kp0 + 2048;
      #pragma unroll
      for (int kk = 0; kk < 2; ++kk) {
        int off = kk * 64 + lhi * 16;
        f16x8 k0 = *(const f16x8*)(kp0 + (off ^ kswz));
        f16x8 k1 = *(const f16x8*)(kp1 + (off ^ kswz));
        s0 = __builtin_amdgcn_mfma_f32_16x16x32_f16(k0, qreg[kk], s0, 0, 0, 0);
        s1 = __builtin_amdgcn_mfma_f32_16x16x32_f16(k1, qreg[kk], s1, 0, 0, 0);
      }
    }

    // --- column bias c_j (always) ---
    {
      const float4 cA = *(const float4*)&cb[t0 + lhi * 4];
      const float4 cB = *(const float4*)&cb[t0 + 16 + lhi * 4];
      s0[0] += cA.x; s0[1] += cA.y; s0[2] += cA.z; s0[3] += cA.w;
      s1[0] += cB.x; s1[1] += cB.y; s1[2] += cB.z; s1[3] += cB.w;
    }
    // --- mask add (block-sparse gated) ---
    if (flg[it]) {
      const float4 mA = *(const float4*)&mask[mrow_base + t0 + lhi * 4];
      const float4 mB = *(const float4*)&mask[mrow_base + t0 + 16 + lhi * 4];
      s0[0] += mA.x; s0[1] += mA.y; s0[2] += mA.z; s0[3] += mA.w;
      s1[0] += mB.x; s1[1] += mB.y; s1[2] += mB.z; s1[3] += mB.w;
    }

    // --- in-warp softmax ---
    float pmax = fmaxf(fmaxf(fmaxf(s0[0], s0[1]), fmaxf(s0[2], s0[3])),
                       fmaxf(fmaxf(s1[0], s1[1]), fmaxf(s1[2], s1[3])));
    pmax = fmaxf(pmax, __shfl_xor(pmax, 16));
    pmax = fmaxf(pmax, __shfl_xor(pmax, 32));

    if (__any(pmax - m_reg > 8.0f)) {  // defer-max (T13)
      float mn = fmaxf(m_reg, pmax);
      float al = __expf(m_reg - mn);
      m_reg = mn;
      l_reg *= al;
      float av[4];
      #pragma unroll
      for (int r = 0; r < 4; ++r) av[r] = __shfl(al, lhi * 4 + r);
      #pragma unroll
      for (int f = 0; f < 4; ++f)
        #pragma unroll
        for (int r = 0; r < 4; ++r) acc[f][r] *= av[r];
    }

    float p[8];
    #pragma unroll
    for (int r = 0; r < 4; ++r) p[r] = __expf(s0[r] - m_reg);
    #pragma unroll
    for (int r = 0; r < 4; ++r) p[4 + r] = __expf(s1[r] - m_reg);
    float psum = ((p[0] + p[1]) + (p[2] + p[3])) + ((p[4] + p[5]) + (p[6] + p[7]));
    psum += __shfl_xor(psum, 16);
    psum += __shfl_xor(psum, 32);
    l_reg += psum;

    // --- VW fragments for this tile (L2 reads) ---
    uint4 vwf[4];
    #pragma unroll
    for (int f = 0; f < 4; ++f)
      vwf[f] = *(const uint4*)(vwb + ((size_t)(lrow + 16 * f)) * SS + t0 + lhi * 8);

    // --- P -> warp-private LDS roundtrip ---
    {
      uint2 pw0, pw1;
      pw0.x = (u32)f2h(p[0]) | ((u32)f2h(p[1]) << 16);
      pw0.y = (u32)f2h(p[2]) | ((u32)f2h(p[3]) << 16);
      pw1.x = (u32)f2h(p[4]) | ((u32)f2h(p[5]) << 16);
      pw1.y = (u32)f2h(p[6]) | ((u32)f2h(p[7]) << 16);
      *(uint2*)&PsW[lrow * 36 + lhi * 4] = pw0;
      *(uint2*)&PsW[lrow * 36 + 16 + lhi * 4] = pw1;
    }
    f16x8 pa = *(const f16x8*)&PsW[lrow * 36 + lhi * 8];

    // --- PV: O += P @ VW (d=64 -> 4 MFMA) ---
    #pragma unroll
    for (int f = 0; f < 4; ++f) {
      f16x8 bfr = __builtin_bit_cast(f16x8, vwf[f]);
      acc[f] = __builtin_amdgcn_mfma_f32_16x16x32_f16(pa, bfr, acc[f], 0, 0, 0);
    }

    // --- single sync point per tile ---
    asm volatile("s_waitcnt vmcnt(0)" ::: "memory");
    __syncthreads();
  }

  // ---- epilogue: normalized partial (fp32) + (m, l) stats ----
  if (lhi == 0) {
    float2* st = (float2*)stats;
    st[(size_t)qt * (BB * SS) + (size_t)b * SS + q0 + w * 16 + lrow] =
        make_float2(m_reg, l_reg);
  }
  float rl[4];
  #pragma unroll
  for (int r = 0; r < 4; ++r) rl[r] = 1.0f / __shfl(l_reg, lhi * 4 + r);
  #pragma unroll
  for (int r = 0; r < 4; ++r) {
    size_t base = ((size_t)qt * (BB * SS) + (size_t)b * SS +
                   (size_t)(q0 + w * 16 + lhi * 4 + r)) * 64 + (size_t)lrow;
    #pragma unroll
    for (int f = 0; f < 4; ++f) opart[base + f * 16] = acc[f][r] * rl[r];
  }
}

// ---------------- K3: merge 4 KV-quarters, add bo ----------------
__global__ __launch_bounds__(256) void merge4(
    const float* __restrict__ opart, const float* __restrict__ stats,
    const float* __restrict__ bo, float* __restrict__ out) {
  const int gid = blockIdx.x * 256 + threadIdx.x;
  const int row = gid >> 3;
  const int c8 = (gid & 7) * 8;
  const float2* st = (const float2*)stats;
  float2 sq[4];
  #pragma unroll
  for (int q = 0; q < 4; ++q) sq[q] = st[(size_t)q * (BB * SS) + row];
  float M = fmaxf(fmaxf(sq[0].x, sq[1].x), fmaxf(sq[2].x, sq[3].x));
  float wv[4], Ssum = 0.f;
  #pragma unroll
  for (int q = 0; q < 4; ++q) {
    wv[q] = __expf(sq[q].x - M) * sq[q].y;
    Ssum += wv[q];
  }
  const float inv = 0.35355339059327373f / Ssum;
  #pragma unroll
  for (int q = 0; q < 4; ++q) wv[q] *= inv;

  float o[8];
  #pragma unroll
  for (int j = 0; j < 8; ++j) o[j] = bo[c8 + j];
  #pragma unroll
  for (int q = 0; q < 4; ++q) {
    const float* op = opart + ((size_t)q * (BB * SS) + row) * 64 + c8;
    float4 a = *(const float4*)op;
    float4 bq4 = *(const float4*)(op + 4);
    o[0] += wv[q] * a.x; o[1] += wv[q] * a.y; o[2] += wv[q] * a.z; o[3] += wv[q] * a.w;
    o[4] += wv[q] * bq4.x; o[5] += wv[q] * bq4.y; o[6] += wv[q] * bq4.z; o[7] += wv[q] * bq4.w;
  }
  float* dst = out + (size_t)row * EE + c8;
  *(float4*)dst = make_float4(o[0], o[1], o[2], o[3]);
  *(float4*)(dst + 4) = make_float4(o[4], o[5], o[6], o[7]);
}

extern "C" void kernel_launch(void* const* d_in, const int* in_sizes, int n_in,
                              void* d_out, int out_size, void* d_ws, size_t ws_size,
                              hipStream_t stream) {
  const float* x = (const float*)d_in[0];
  const float* mask = (const float*)d_in[1];
  const float* Wq = (const float*)d_in[2];
  const float* bq = (const float*)d_in[3];
  const float* Wk = (const float*)d_in[4];
  const float* bk = (const float*)d_in[5];  // folded out: row-const cancels
  const float* Wv = (const float*)d_in[6];
  const float* bv = (const float*)d_in[7];
  const float* Wo = (const float*)d_in[8];
  const float* bo = (const float*)d_in[9];
  float* out = (float*)d_out;
  (void)bk;

  const size_t N64 = (size_t)BB * SS * 64;
  u16* ubuf = (u16*)d_ws;
  u16* xhh = ubuf + N64;
  u16* vwt = xhh + N64;
  float* cbuf = (float*)(vwt + N64);
  float* G = cbuf + (size_t)BB * SS;
  float* g2 = G + 64 * 64;
  float* Wf = g2 + 64;
  float* bf = Wf + 64 * 64;
  float* opart = bf + 64;                        // 4 * BB*SS*64 f32
  float* st = opart + (size_t)4 * BB * SS * 64;  // 4 * BB*SS float2
  unsigned char* flags = (unsigned char*)(st + (size_t)8 * BB * SS);  // 16 KB

  gfuse<<<65, 256, 0, stream>>>(Wq, bq, Wk, G, g2);
  wfuse<<<65, 256, 0, stream>>>(Wv, bv, Wo, Wf, bf);
  uc_proj<<<BB * SS / 64, 256, 0, stream>>>(x, G, g2, ubuf, xhh, cbuf);
  vw_proj<<<BB * SS / 64, 256, 0, stream>>>(x, Wf, bf, vwt);
  mask_scan<<<512, 256, 0, stream>>>(mask, flags);
  attn_fwd<<<512, 512, 17408, stream>>>(ubuf, xhh, vwt, cbuf, mask, flags, opart, st);
  merge4<<<BB * SS * 8 / 256, 256, 0, stream>>>(opart, st, bo, out);
}

// Round 17
// 202.710 us; speedup vs baseline: 2.5389x; 1.0679x over previous
//
#include <hip/hip_runtime.h>
#include <hip/hip_bf16.h>

#define BB 4
#define SS 4096
#define EE 64
#define DD 512
#define KVBLK 64
#define NQT 16  // 64-wide KV tiles per quarter

typedef __attribute__((ext_vector_type(4))) float f32x4;
typedef __attribute__((ext_vector_type(8))) _Float16 f16x8;
typedef unsigned short u16;
typedef unsigned int u32;

__device__ __forceinline__ u16 f2h(float f) {
  _Float16 h = (_Float16)f;
  return __builtin_bit_cast(u16, h);
}
__device__ __forceinline__ float h2f(u16 b) {
  return (float)__builtin_bit_cast(_Float16, b);
}

__device__ __forceinline__ void async16(const void* g, void* l) {
  __builtin_amdgcn_global_load_lds(
      (const __attribute__((address_space(1))) void*)g,
      (__attribute__((address_space(3))) void*)l, 16, 0, 0);
}

// ---------------- K1: fused weight-fold: G=Wq@Wk^T, g2=Wk@bq, Wf=Wv@Wo, bf=bv@Wo ----
// 130 blocks: e<64 -> G[e]; e==64 -> g2; 65<=e<130 -> Wf[e-65]; e==129 -> bf.
__global__ __launch_bounds__(256) void wgfuse(
    const float* __restrict__ Wq, const float* __restrict__ bq,
    const float* __restrict__ Wk, const float* __restrict__ Wv,
    const float* __restrict__ bv, const float* __restrict__ Wo,
    float* __restrict__ G, float* __restrict__ g2,
    float* __restrict__ Wf, float* __restrict__ bf) {
  __shared__ float red[4][64];
  const int tid = threadIdx.x;
  const int d = tid & 63, kq = tid >> 6;
  const int e = blockIdx.x;
  float a = 0.f;
  if (e < 65) {
    const float* src = (e < 64) ? &Wq[(size_t)e * DD] : bq;
    #pragma unroll 4
    for (int k = kq * 128; k < (kq + 1) * 128; ++k)
      a += src[k] * Wk[(size_t)d * DD + k];
  } else {
    const int e2 = e - 65;
    const float* src = (e2 < 64) ? &Wv[(size_t)e2 * DD] : bv;
    #pragma unroll 4
    for (int k = kq * 128; k < (kq + 1) * 128; ++k)
      a += src[k] * Wo[(size_t)k * EE + d];
  }
  red[kq][d] = a;
  __syncthreads();
  if (tid < 64) {
    float s = (red[0][tid] + red[1][tid]) + (red[2][tid] + red[3][tid]);
    if (e < 64) G[e * 64 + tid] = s;
    else if (e == 64) g2[tid] = s;
    else if (e < 129) Wf[(e - 65) * EE + tid] = s;
    else bf[tid] = s;
  }
}

// ---------------- K2: fused projections: u=x@G (fp16), c=x@g2, xh=fp16(x),
//                  VWt[b][d][s]=(x@Wf+bf)^T (fp16) ----------------
__global__ __launch_bounds__(256) void proj64(
    const float* __restrict__ x, const float* __restrict__ G,
    const float* __restrict__ g2, const float* __restrict__ Wf,
    const float* __restrict__ bf, u16* __restrict__ ubuf,
    u16* __restrict__ xh, float* __restrict__ cbuf, u16* __restrict__ vwt) {
  __shared__ float xs[64][EE];
  __shared__ float gs[EE][64];
  __shared__ float wfs[EE][64];
  __shared__ float g2s[64];
  __shared__ float bfs[64];
  const int tid = threadIdx.x;
  const int b = blockIdx.x & 3;
  const int s0 = (blockIdx.x >> 2) * 64;

  #pragma unroll
  for (int i = 0; i < 4; ++i) {
    int idx = tid + 256 * i;
    int r = idx >> 4, c = (idx & 15) * 4;
    *(float4*)&xs[r][c] = *(const float4*)&x[((size_t)b * SS + s0 + r) * EE + c];
    *(float4*)&gs[r][c] = *(const float4*)&G[(size_t)r * 64 + c];
    *(float4*)&wfs[r][c] = *(const float4*)&Wf[(size_t)r * 64 + c];
  }
  if (tid < 64) { g2s[tid] = g2[tid]; bfs[tid] = bf[tid]; }
  __syncthreads();

  const int d = tid & 63, sg = tid >> 6;
  // u = x @ G
  {
    float acc[16];
    #pragma unroll
    for (int i = 0; i < 16; ++i) acc[i] = 0.f;
    for (int e = 0; e < EE; ++e) {
      float gv = gs[e][d];
      #pragma unroll
      for (int i = 0; i < 16; ++i) acc[i] += xs[sg * 16 + i][e] * gv;
    }
    #pragma unroll
    for (int i = 0; i < 16; ++i)
      ubuf[((size_t)b * SS + s0 + sg * 16 + i) * 64 + d] = f2h(acc[i]);
  }
  // vw = (x @ Wf + bf)^T
  {
    float acc[16];
    #pragma unroll
    for (int i = 0; i < 16; ++i) acc[i] = bfs[d];
    for (int e = 0; e < EE; ++e) {
      float wv = wfs[e][d];
      #pragma unroll
      for (int i = 0; i < 16; ++i) acc[i] += xs[sg * 16 + i][e] * wv;
    }
    u16* dst = vwt + ((size_t)b * 64 + d) * SS + s0 + sg * 16;
    union { uint4 u[2]; u16 hh[16]; } o;
    #pragma unroll
    for (int i = 0; i < 16; ++i) o.hh[i] = f2h(acc[i]);
    *(uint4*)dst = o.u[0];
    *(uint4*)(dst + 8) = o.u[1];
  }
  // c = x @ g2
  if (tid < 64) {
    float cc = 0.f;
    #pragma unroll 8
    for (int e = 0; e < EE; ++e) cc += xs[tid][e] * g2s[e];
    cbuf[(size_t)b * SS + s0 + tid] = cc;
  }
  // xh = fp16(x)
  #pragma unroll
  for (int i = 0; i < 16; ++i) {
    int idx = tid + 256 * i;
    int r = idx >> 6, dd = idx & 63;
    xh[((size_t)b * SS + s0 + r) * 64 + dd] = f2h(xs[r][dd]);
  }
}

// ---------------- K3: mask block-sparsity scan ----------------
__global__ __launch_bounds__(256) void mask_scan(
    const float* __restrict__ mask, unsigned char* __restrict__ flags) {
  __shared__ int fl[32];
  const int tid = threadIdx.x;
  const int bid = blockIdx.x;
  const int tq = bid & 3;          // t-quarter (1024 floats)
  const int qb = (bid >> 2) & 31;  // q-block of 128 rows
  const int b = bid >> 7;
  if (tid < 32) fl[tid] = 0;
  __syncthreads();
  const size_t rbase = ((size_t)(b * SS + qb * 128)) * SS + tq * 1024 + tid * 4;
  #pragma unroll 1
  for (int r = 0; r < 128; ++r) {
    float4 v = *(const float4*)&mask[rbase + (size_t)r * SS];
    int nz = (v.x != 0.f) | (v.y != 0.f) | (v.z != 0.f) | (v.w != 0.f);
    nz |= __shfl_xor(nz, 1);
    nz |= __shfl_xor(nz, 2);
    nz |= __shfl_xor(nz, 4);
    if (nz && ((tid & 7) == 0)) atomicOr(&fl[tid >> 3], 1);
  }
  __syncthreads();
  if (tid < 32)
    flags[((size_t)(b * 32 + qb)) * 128 + tq * 32 + tid] = (unsigned char)fl[tid];
}

// ---------------- K4: flash attention v14 (D=64 QK, 64-wide KV tiles) ----------------
// scores = u_i . x_j + c_j (+ mask). 512 blocks x 512 thr (8 warps x 16q),
// 2 blocks/CU. 16 iters of 64-t tiles: 8 QK MFMA + 8 PV MFMA per iter, ONE
// vmcnt+barrier per iter. LDS: Ks[2][64][64] 16K | Ps[8][16][72] 18K = 35 KiB.
__global__ __launch_bounds__(512, 4) void attn_fwd(
    const u16* __restrict__ ubuf, const u16* __restrict__ xh,
    const u16* __restrict__ vwt, const float* __restrict__ cbuf,
    const float* __restrict__ mask, const unsigned char* __restrict__ flags,
    float* __restrict__ opart, float* __restrict__ stats) {
  extern __shared__ char smem[];
  u16* PsS = (u16*)(smem + 16384);

  const int tid = threadIdx.x;
  const int lane = tid & 63;
  const int w = tid >> 6;  // 0..7
  const int lrow = lane & 15, lhi = lane >> 4;

  const int bid = blockIdx.x;
  const int grp = bid & 15;
  const int b = grp >> 2, qt = grp & 3;
  const int qb = bid >> 4;
  const int q0 = qb * 128;
  const int tbase = qt * (SS / 4);

  const int qrow = q0 + w * 16 + lrow;

  // ---- u -> registers (B-operand frags, D=64 -> 2 kk steps) ----
  f16x8 qreg[2];
  {
    const u16* qg = ubuf + ((size_t)b * SS + qrow) * 64 + lhi * 8;
    qreg[0] = *(const f16x8*)(qg);
    qreg[1] = *(const f16x8*)(qg + 32);
  }

  // stage a 64x64 fp16 x-tile (8KB): 512 threads x 16B.
  auto stage_k = [&](int t0n, int buf) {
    const char* kg = (const char*)(xh + ((size_t)b * SS + t0n) * 64);
    const int row = w * 8 + (lane >> 3);
    const int ch = lane & 7;
    async16(kg + (size_t)row * 128 + ((ch * 16) ^ ((row & 7) << 4)),
            (char*)smem + buf * 8192 + row * 128);
  };

  float m_reg = -3.0e38f, l_reg = 0.f;
  f32x4 acc[4];
  #pragma unroll
  for (int f = 0; f < 4; ++f) acc[f] = (f32x4){0.f, 0.f, 0.f, 0.f};

  const u16* vwb = vwt + (size_t)b * 64 * SS;
  const float* cb = cbuf + (size_t)b * SS;
  const size_t mrow_base = ((size_t)b * SS + qrow) * SS;
  const unsigned char* flg = flags + ((size_t)(b * 32 + qb)) * 128 + qt * 32;

  // ---- prologue: K(0) -> buf0 ----
  stage_k(tbase, 0);
  asm volatile("s_waitcnt vmcnt(0)" ::: "memory");
  __syncthreads();

  u16* PsW = PsS + w * 1152;  // warp-private [16][72]
  const int kswz = (lrow & 7) << 4;

  #pragma unroll 1
  for (int it = 0; it < NQT; ++it) {
    const int buf = it & 1;
    const int t0 = tbase + it * KVBLK;

    // --- stage NEXT x-tile (full-tile cover) ---
    if (it + 1 < NQT) stage_k(t0 + KVBLK, buf ^ 1);

    // --- QK^T swapped over D=64: 4 t-chains x 2 kk ---
    f32x4 s[4];
    #pragma unroll
    for (int ch = 0; ch < 4; ++ch) s[ch] = (f32x4){0.f, 0.f, 0.f, 0.f};
    {
      const char* kpb = (const char*)smem + buf * 8192 + lrow * 128;
      __builtin_amdgcn_s_setprio(1);
      #pragma unroll
      for (int kk = 0; kk < 2; ++kk) {
        int off = (kk * 64 + lhi * 16) ^ kswz;
        #pragma unroll
        for (int ch = 0; ch < 4; ++ch) {
          f16x8 kf = *(const f16x8*)(kpb + ch * 2048 + off);
          s[ch] = __builtin_amdgcn_mfma_f32_16x16x32_f16(kf, qreg[kk], s[ch], 0, 0, 0);
        }
      }
      __builtin_amdgcn_s_setprio(0);
    }

    // --- column bias c_j ---
    #pragma unroll
    for (int ch = 0; ch < 4; ++ch) {
      const float4 cv = *(const float4*)&cb[t0 + ch * 16 + lhi * 4];
      s[ch][0] += cv.x; s[ch][1] += cv.y; s[ch][2] += cv.z; s[ch][3] += cv.w;
    }
    // --- mask add (block-sparse gated; two 32-t flags per 64-t tile) ---
    if (flg[2 * it] | flg[2 * it + 1]) {
      #pragma unroll
      for (int ch = 0; ch < 4; ++ch) {
        const float4 mv = *(const float4*)&mask[mrow_base + t0 + ch * 16 + lhi * 4];
        s[ch][0] += mv.x; s[ch][1] += mv.y; s[ch][2] += mv.z; s[ch][3] += mv.w;
      }
    }

    // --- in-warp softmax over 64 t ---
    float pmax = -3.0e38f;
    #pragma unroll
    for (int ch = 0; ch < 4; ++ch)
      pmax = fmaxf(pmax, fmaxf(fmaxf(s[ch][0], s[ch][1]), fmaxf(s[ch][2], s[ch][3])));
    pmax = fmaxf(pmax, __shfl_xor(pmax, 16));
    pmax = fmaxf(pmax, __shfl_xor(pmax, 32));

    if (__any(pmax - m_reg > 8.0f)) {  // defer-max (T13)
      float mn = fmaxf(m_reg, pmax);
      float al = __expf(m_reg - mn);
      m_reg = mn;
      l_reg *= al;
      float av[4];
      #pragma unroll
      for (int r = 0; r < 4; ++r) av[r] = __shfl(al, lhi * 4 + r);
      #pragma unroll
      for (int f = 0; f < 4; ++f)
        #pragma unroll
        for (int r = 0; r < 4; ++r) acc[f][r] *= av[r];
    }

    float psum = 0.f;
    #pragma unroll
    for (int ch = 0; ch < 4; ++ch) {
      #pragma unroll
      for (int r = 0; r < 4; ++r) s[ch][r] = __expf(s[ch][r] - m_reg);
      psum += (s[ch][0] + s[ch][1]) + (s[ch][2] + s[ch][3]);
    }
    psum += __shfl_xor(psum, 16);
    psum += __shfl_xor(psum, 32);
    l_reg += psum;

    // --- VW fragments (L2 reads): 4 d-frags x 2 t-halves ---
    uint4 vwf[8];
    #pragma unroll
    for (int f = 0; f < 4; ++f) {
      const u16* vp = vwb + ((size_t)(lrow + 16 * f)) * SS + t0 + lhi * 8;
      vwf[2 * f] = *(const uint4*)(vp);
      vwf[2 * f + 1] = *(const uint4*)(vp + 32);
    }

    // --- P -> warp-private LDS roundtrip ---
    #pragma unroll
    for (int ch = 0; ch < 4; ++ch) {
      uint2 pw;
      pw.x = (u32)f2h(s[ch][0]) | ((u32)f2h(s[ch][1]) << 16);
      pw.y = (u32)f2h(s[ch][2]) | ((u32)f2h(s[ch][3]) << 16);
      *(uint2*)&PsW[lrow * 72 + ch * 16 + lhi * 4] = pw;
    }
    f16x8 pa0 = *(const f16x8*)&PsW[lrow * 72 + lhi * 8];
    f16x8 pa1 = *(const f16x8*)&PsW[lrow * 72 + 32 + lhi * 8];

    // --- PV: O += P @ VW (t=64 -> 8 MFMA) ---
    __builtin_amdgcn_s_setprio(1);
    #pragma unroll
    for (int f = 0; f < 4; ++f) {
      f16x8 b0 = __builtin_bit_cast(f16x8, vwf[2 * f]);
      f16x8 b1 = __builtin_bit_cast(f16x8, vwf[2 * f + 1]);
      acc[f] = __builtin_amdgcn_mfma_f32_16x16x32_f16(pa0, b0, acc[f], 0, 0, 0);
      acc[f] = __builtin_amdgcn_mfma_f32_16x16x32_f16(pa1, b1, acc[f], 0, 0, 0);
    }
    __builtin_amdgcn_s_setprio(0);

    // --- single sync point per tile ---
    asm volatile("s_waitcnt vmcnt(0)" ::: "memory");
    __syncthreads();
  }

  // ---- epilogue: normalized partial (fp32) + (m, l) stats ----
  if (lhi == 0) {
    float2* st = (float2*)stats;
    st[(size_t)qt * (BB * SS) + (size_t)b * SS + q0 + w * 16 + lrow] =
        make_float2(m_reg, l_reg);
  }
  float rl[4];
  #pragma unroll
  for (int r = 0; r < 4; ++r) rl[r] = 1.0f / __shfl(l_reg, lhi * 4 + r);
  #pragma unroll
  for (int r = 0; r < 4; ++r) {
    size_t base = ((size_t)qt * (BB * SS) + (size_t)b * SS +
                   (size_t)(q0 + w * 16 + lhi * 4 + r)) * 64 + (size_t)lrow;
    #pragma unroll
    for (int f = 0; f < 4; ++f) opart[base + f * 16] = acc[f][r] * rl[r];
  }
}

// ---------------- K5: merge 4 KV-quarters, add bo ----------------
__global__ __launch_bounds__(256) void merge4(
    const float* __restrict__ opart, const float* __restrict__ stats,
    const float* __restrict__ bo, float* __restrict__ out) {
  const int gid = blockIdx.x * 256 + threadIdx.x;
  const int row = gid >> 3;
  const int c8 = (gid & 7) * 8;
  const float2* st = (const float2*)stats;
  float2 sq[4];
  #pragma unroll
  for (int q = 0; q < 4; ++q) sq[q] = st[(size_t)q * (BB * SS) + row];
  float M = fmaxf(fmaxf(sq[0].x, sq[1].x), fmaxf(sq[2].x, sq[3].x));
  float wv[4], Ssum = 0.f;
  #pragma unroll
  for (int q = 0; q < 4; ++q) {
    wv[q] = __expf(sq[q].x - M) * sq[q].y;
    Ssum += wv[q];
  }
  const float inv = 0.35355339059327373f / Ssum;
  #pragma unroll
  for (int q = 0; q < 4; ++q) wv[q] *= inv;

  float o[8];
  #pragma unroll
  for (int j = 0; j < 8; ++j) o[j] = bo[c8 + j];
  #pragma unroll
  for (int q = 0; q < 4; ++q) {
    const float* op = opart + ((size_t)q * (BB * SS) + row) * 64 + c8;
    float4 a = *(const float4*)op;
    float4 bq4 = *(const float4*)(op + 4);
    o[0] += wv[q] * a.x; o[1] += wv[q] * a.y; o[2] += wv[q] * a.z; o[3] += wv[q] * a.w;
    o[4] += wv[q] * bq4.x; o[5] += wv[q] * bq4.y; o[6] += wv[q] * bq4.z; o[7] += wv[q] * bq4.w;
  }
  float* dst = out + (size_t)row * EE + c8;
  *(float4*)dst = make_float4(o[0], o[1], o[2], o[3]);
  *(float4*)(dst + 4) = make_float4(o[4], o[5], o[6], o[7]);
}

extern "C" void kernel_launch(void* const* d_in, const int* in_sizes, int n_in,
                              void* d_out, int out_size, void* d_ws, size_t ws_size,
                              hipStream_t stream) {
  const float* x = (const float*)d_in[0];
  const float* mask = (const float*)d_in[1];
  const float* Wq = (const float*)d_in[2];
  const float* bq = (const float*)d_in[3];
  const float* Wk = (const float*)d_in[4];
  const float* bk = (const float*)d_in[5];  // folded out: row-const cancels in softmax
  const float* Wv = (const float*)d_in[6];
  const float* bv = (const float*)d_in[7];
  const float* Wo = (const float*)d_in[8];
  const float* bo = (const float*)d_in[9];
  float* out = (float*)d_out;
  (void)bk;

  const size_t N64 = (size_t)BB * SS * 64;
  u16* ubuf = (u16*)d_ws;
  u16* xhh = ubuf + N64;
  u16* vwt = xhh + N64;
  float* cbuf = (float*)(vwt + N64);
  float* G = cbuf + (size_t)BB * SS;
  float* g2 = G + 64 * 64;
  float* Wf = g2 + 64;
  float* bf = Wf + 64 * 64;
  float* opart = bf + 64;                        // 4 * BB*SS*64 f32
  float* st = opart + (size_t)4 * BB * SS * 64;  // 4 * BB*SS float2
  unsigned char* flags = (unsigned char*)(st + (size_t)8 * BB * SS);  // 16 KB

  wgfuse<<<130, 256, 0, stream>>>(Wq, bq, Wk, Wv, bv, Wo, G, g2, Wf, bf);
  proj64<<<BB * SS / 64, 256, 0, stream>>>(x, G, g2, Wf, bf, ubuf, xhh, cbuf, vwt);
  mask_scan<<<512, 256, 0, stream>>>(mask, flags);
  attn_fwd<<<512, 512, 34816, stream>>>(ubuf, xhh, vwt, cbuf, mask, flags, opart, st);
  merge4<<<BB * SS * 8 / 256, 256, 0, stream>>>(opart, st, bo, out);
}

// Round 18
// 188.682 us; speedup vs baseline: 2.7276x; 1.0743x over previous
//
#include <hip/hip_runtime.h>
#include <hip/hip_bf16.h>

#define BB 4
#define SS 4096
#define EE 64
#define DD 512
#define KVBLK 64
#define NQT 16  // 64-wide KV tiles per quarter

typedef __attribute__((ext_vector_type(4))) float f32x4;
typedef __attribute__((ext_vector_type(8))) _Float16 f16x8;
typedef unsigned short u16;
typedef unsigned int u32;

__device__ __forceinline__ u16 f2h(float f) {
  _Float16 h = (_Float16)f;
  return __builtin_bit_cast(u16, h);
}
__device__ __forceinline__ float h2f(u16 b) {
  return (float)__builtin_bit_cast(_Float16, b);
}

__device__ __forceinline__ void async16(const void* g, void* l) {
  __builtin_amdgcn_global_load_lds(
      (const __attribute__((address_space(1))) void*)g,
      (__attribute__((address_space(3))) void*)l, 16, 0, 0);
}

// ---------------- K1: fused weight-fold: G=Wq@Wk^T, g2=Wk@bq, Wf=Wv@Wo, bf=bv@Wo ----
__global__ __launch_bounds__(256) void wgfuse(
    const float* __restrict__ Wq, const float* __restrict__ bq,
    const float* __restrict__ Wk, const float* __restrict__ Wv,
    const float* __restrict__ bv, const float* __restrict__ Wo,
    float* __restrict__ G, float* __restrict__ g2,
    float* __restrict__ Wf, float* __restrict__ bf) {
  __shared__ float red[4][64];
  const int tid = threadIdx.x;
  const int d = tid & 63, kq = tid >> 6;
  const int e = blockIdx.x;
  float a = 0.f;
  if (e < 65) {
    const float* src = (e < 64) ? &Wq[(size_t)e * DD] : bq;
    #pragma unroll 4
    for (int k = kq * 128; k < (kq + 1) * 128; ++k)
      a += src[k] * Wk[(size_t)d * DD + k];
  } else {
    const int e2 = e - 65;
    const float* src = (e2 < 64) ? &Wv[(size_t)e2 * DD] : bv;
    #pragma unroll 4
    for (int k = kq * 128; k < (kq + 1) * 128; ++k)
      a += src[k] * Wo[(size_t)k * EE + d];
  }
  red[kq][d] = a;
  __syncthreads();
  if (tid < 64) {
    float s = (red[0][tid] + red[1][tid]) + (red[2][tid] + red[3][tid]);
    if (e < 64) G[e * 64 + tid] = s;
    else if (e == 64) g2[tid] = s;
    else if (e < 129) Wf[(e - 65) * EE + tid] = s;
    else bf[tid] = s;
  }
}

// ---------------- K2: grid-fused prep: mask_scan (bid<512) + proj64 (bid>=512) ----
// mask_scan: streams mask contiguously -> per-(b,128q,32t) nonzero flags.
// proj64: u=x@G (fp16), c=x@g2, xh=fp16(x), VWt=(x@Wf+bf)^T (fp16).
// Independent inputs -> overlap BW-bound scan with VALU-bound projections.
__global__ __launch_bounds__(256) void prep(
    const float* __restrict__ x, const float* __restrict__ G,
    const float* __restrict__ g2, const float* __restrict__ Wf,
    const float* __restrict__ bf, const float* __restrict__ mask,
    u16* __restrict__ ubuf, u16* __restrict__ xh, float* __restrict__ cbuf,
    u16* __restrict__ vwt, unsigned char* __restrict__ flags) {
  __shared__ float xs[64][EE];
  __shared__ float gs[EE][64];
  __shared__ float wfs[EE][64];
  __shared__ float g2s[64];
  __shared__ float bfs[64];
  __shared__ int fl[32];
  const int tid = threadIdx.x;

  if (blockIdx.x < 512) {
    // ---- mask_scan body ----
    const int bid = blockIdx.x;
    const int tq = bid & 3;          // t-quarter (1024 floats)
    const int qb = (bid >> 2) & 31;  // q-block of 128 rows
    const int b = bid >> 7;
    if (tid < 32) fl[tid] = 0;
    __syncthreads();
    const size_t rbase = ((size_t)(b * SS + qb * 128)) * SS + tq * 1024 + tid * 4;
    #pragma unroll 1
    for (int r = 0; r < 128; ++r) {
      float4 v = *(const float4*)&mask[rbase + (size_t)r * SS];
      int nz = (v.x != 0.f) | (v.y != 0.f) | (v.z != 0.f) | (v.w != 0.f);
      nz |= __shfl_xor(nz, 1);
      nz |= __shfl_xor(nz, 2);
      nz |= __shfl_xor(nz, 4);
      if (nz && ((tid & 7) == 0)) atomicOr(&fl[tid >> 3], 1);
    }
    __syncthreads();
    if (tid < 32)
      flags[((size_t)(b * 32 + qb)) * 128 + tq * 32 + tid] = (unsigned char)fl[tid];
    return;
  }

  // ---- proj64 body ----
  const int bid = blockIdx.x - 512;
  const int b = bid & 3;
  const int s0 = (bid >> 2) * 64;

  #pragma unroll
  for (int i = 0; i < 4; ++i) {
    int idx = tid + 256 * i;
    int r = idx >> 4, c = (idx & 15) * 4;
    *(float4*)&xs[r][c] = *(const float4*)&x[((size_t)b * SS + s0 + r) * EE + c];
    *(float4*)&gs[r][c] = *(const float4*)&G[(size_t)r * 64 + c];
    *(float4*)&wfs[r][c] = *(const float4*)&Wf[(size_t)r * 64 + c];
  }
  if (tid < 64) { g2s[tid] = g2[tid]; bfs[tid] = bf[tid]; }
  __syncthreads();

  const int d = tid & 63, sg = tid >> 6;
  // u = x @ G
  {
    float acc[16];
    #pragma unroll
    for (int i = 0; i < 16; ++i) acc[i] = 0.f;
    for (int e = 0; e < EE; ++e) {
      float gv = gs[e][d];
      #pragma unroll
      for (int i = 0; i < 16; ++i) acc[i] += xs[sg * 16 + i][e] * gv;
    }
    #pragma unroll
    for (int i = 0; i < 16; ++i)
      ubuf[((size_t)b * SS + s0 + sg * 16 + i) * 64 + d] = f2h(acc[i]);
  }
  // vw = (x @ Wf + bf)^T
  {
    float acc[16];
    #pragma unroll
    for (int i = 0; i < 16; ++i) acc[i] = bfs[d];
    for (int e = 0; e < EE; ++e) {
      float wv = wfs[e][d];
      #pragma unroll
      for (int i = 0; i < 16; ++i) acc[i] += xs[sg * 16 + i][e] * wv;
    }
    u16* dst = vwt + ((size_t)b * 64 + d) * SS + s0 + sg * 16;
    union { uint4 u[2]; u16 hh[16]; } o;
    #pragma unroll
    for (int i = 0; i < 16; ++i) o.hh[i] = f2h(acc[i]);
    *(uint4*)dst = o.u[0];
    *(uint4*)(dst + 8) = o.u[1];
  }
  // c = x @ g2
  if (tid < 64) {
    float cc = 0.f;
    #pragma unroll 8
    for (int e = 0; e < EE; ++e) cc += xs[tid][e] * g2s[e];
    cbuf[(size_t)b * SS + s0 + tid] = cc;
  }
  // xh = fp16(x)
  #pragma unroll
  for (int i = 0; i < 16; ++i) {
    int idx = tid + 256 * i;
    int r = idx >> 6, dd = idx & 63;
    xh[((size_t)b * SS + s0 + r) * 64 + dd] = f2h(xs[r][dd]);
  }
}

// ---------------- K3: flash attention v14 (D=64 QK, 64-wide KV tiles) ----------------
// scores = u_i . x_j + c_j (+ mask). 512 blocks x 512 thr (8 warps x 16q),
// 2 blocks/CU. 16 iters of 64-t tiles: 8 QK MFMA + 8 PV MFMA per iter, ONE
// vmcnt+barrier per iter. LDS: Ks[2][64][64] 16K | Ps[8][16][72] 18K = 35 KiB.
__global__ __launch_bounds__(512, 4) void attn_fwd(
    const u16* __restrict__ ubuf, const u16* __restrict__ xh,
    const u16* __restrict__ vwt, const float* __restrict__ cbuf,
    const float* __restrict__ mask, const unsigned char* __restrict__ flags,
    float* __restrict__ opart, float* __restrict__ stats) {
  extern __shared__ char smem[];
  u16* PsS = (u16*)(smem + 16384);

  const int tid = threadIdx.x;
  const int lane = tid & 63;
  const int w = tid >> 6;  // 0..7
  const int lrow = lane & 15, lhi = lane >> 4;

  const int bid = blockIdx.x;
  const int grp = bid & 15;
  const int b = grp >> 2, qt = grp & 3;
  const int qb = bid >> 4;
  const int q0 = qb * 128;
  const int tbase = qt * (SS / 4);

  const int qrow = q0 + w * 16 + lrow;

  // ---- u -> registers (B-operand frags, D=64 -> 2 kk steps) ----
  f16x8 qreg[2];
  {
    const u16* qg = ubuf + ((size_t)b * SS + qrow) * 64 + lhi * 8;
    qreg[0] = *(const f16x8*)(qg);
    qreg[1] = *(const f16x8*)(qg + 32);
  }

  // stage a 64x64 fp16 x-tile (8KB): 512 threads x 16B.
  auto stage_k = [&](int t0n, int buf) {
    const char* kg = (const char*)(xh + ((size_t)b * SS + t0n) * 64);
    const int row = w * 8 + (lane >> 3);
    const int ch = lane & 7;
    async16(kg + (size_t)row * 128 + ((ch * 16) ^ ((row & 7) << 4)),
            (char*)smem + buf * 8192 + row * 128);
  };

  float m_reg = -3.0e38f, l_reg = 0.f;
  f32x4 acc[4];
  #pragma unroll
  for (int f = 0; f < 4; ++f) acc[f] = (f32x4){0.f, 0.f, 0.f, 0.f};

  const u16* vwb = vwt + (size_t)b * 64 * SS;
  const float* cb = cbuf + (size_t)b * SS;
  const size_t mrow_base = ((size_t)b * SS + qrow) * SS;
  const unsigned char* flg = flags + ((size_t)(b * 32 + qb)) * 128 + qt * 32;

  // ---- prologue: K(0) -> buf0 ----
  stage_k(tbase, 0);
  asm volatile("s_waitcnt vmcnt(0)" ::: "memory");
  __syncthreads();

  u16* PsW = PsS + w * 1152;  // warp-private [16][72]
  const int kswz = (lrow & 7) << 4;

  #pragma unroll 1
  for (int it = 0; it < NQT; ++it) {
    const int buf = it & 1;
    const int t0 = tbase + it * KVBLK;

    // --- stage NEXT x-tile (full-tile cover) ---
    if (it + 1 < NQT) stage_k(t0 + KVBLK, buf ^ 1);

    // --- QK^T swapped over D=64: 4 t-chains x 2 kk ---
    f32x4 s[4];
    #pragma unroll
    for (int ch = 0; ch < 4; ++ch) s[ch] = (f32x4){0.f, 0.f, 0.f, 0.f};
    {
      const char* kpb = (const char*)smem + buf * 8192 + lrow * 128;
      __builtin_amdgcn_s_setprio(1);
      #pragma unroll
      for (int kk = 0; kk < 2; ++kk) {
        int off = (kk * 64 + lhi * 16) ^ kswz;
        #pragma unroll
        for (int ch = 0; ch < 4; ++ch) {
          f16x8 kf = *(const f16x8*)(kpb + ch * 2048 + off);
          s[ch] = __builtin_amdgcn_mfma_f32_16x16x32_f16(kf, qreg[kk], s[ch], 0, 0, 0);
        }
      }
      __builtin_amdgcn_s_setprio(0);
    }

    // --- column bias c_j ---
    #pragma unroll
    for (int ch = 0; ch < 4; ++ch) {
      const float4 cv = *(const float4*)&cb[t0 + ch * 16 + lhi * 4];
      s[ch][0] += cv.x; s[ch][1] += cv.y; s[ch][2] += cv.z; s[ch][3] += cv.w;
    }
    // --- mask add (block-sparse gated; two 32-t flags per 64-t tile) ---
    if (flg[2 * it] | flg[2 * it + 1]) {
      #pragma unroll
      for (int ch = 0; ch < 4; ++ch) {
        const float4 mv = *(const float4*)&mask[mrow_base + t0 + ch * 16 + lhi * 4];
        s[ch][0] += mv.x; s[ch][1] += mv.y; s[ch][2] += mv.z; s[ch][3] += mv.w;
      }
    }

    // --- in-warp softmax over 64 t ---
    float pmax = -3.0e38f;
    #pragma unroll
    for (int ch = 0; ch < 4; ++ch)
      pmax = fmaxf(pmax, fmaxf(fmaxf(s[ch][0], s[ch][1]), fmaxf(s[ch][2], s[ch][3])));
    pmax = fmaxf(pmax, __shfl_xor(pmax, 16));
    pmax = fmaxf(pmax, __shfl_xor(pmax, 32));

    if (__any(pmax - m_reg > 8.0f)) {  // defer-max (T13)
      float mn = fmaxf(m_reg, pmax);
      float al = __expf(m_reg - mn);
      m_reg = mn;
      l_reg *= al;
      float av[4];
      #pragma unroll
      for (int r = 0; r < 4; ++r) av[r] = __shfl(al, lhi * 4 + r);
      #pragma unroll
      for (int f = 0; f < 4; ++f)
        #pragma unroll
        for (int r = 0; r < 4; ++r) acc[f][r] *= av[r];
    }

    float psum = 0.f;
    #pragma unroll
    for (int ch = 0; ch < 4; ++ch) {
      #pragma unroll
      for (int r = 0; r < 4; ++r) s[ch][r] = __expf(s[ch][r] - m_reg);
      psum += (s[ch][0] + s[ch][1]) + (s[ch][2] + s[ch][3]);
    }
    psum += __shfl_xor(psum, 16);
    psum += __shfl_xor(psum, 32);
    l_reg += psum;

    // --- VW fragments (L2 reads): 4 d-frags x 2 t-halves ---
    uint4 vwf[8];
    #pragma unroll
    for (int f = 0; f < 4; ++f) {
      const u16* vp = vwb + ((size_t)(lrow + 16 * f)) * SS + t0 + lhi * 8;
      vwf[2 * f] = *(const uint4*)(vp);
      vwf[2 * f + 1] = *(const uint4*)(vp + 32);
    }

    // --- P -> warp-private LDS roundtrip ---
    #pragma unroll
    for (int ch = 0; ch < 4; ++ch) {
      uint2 pw;
      pw.x = (u32)f2h(s[ch][0]) | ((u32)f2h(s[ch][1]) << 16);
      pw.y = (u32)f2h(s[ch][2]) | ((u32)f2h(s[ch][3]) << 16);
      *(uint2*)&PsW[lrow * 72 + ch * 16 + lhi * 4] = pw;
    }
    f16x8 pa0 = *(const f16x8*)&PsW[lrow * 72 + lhi * 8];
    f16x8 pa1 = *(const f16x8*)&PsW[lrow * 72 + 32 + lhi * 8];

    // --- PV: O += P @ VW (t=64 -> 8 MFMA) ---
    __builtin_amdgcn_s_setprio(1);
    #pragma unroll
    for (int f = 0; f < 4; ++f) {
      f16x8 b0 = __builtin_bit_cast(f16x8, vwf[2 * f]);
      f16x8 b1 = __builtin_bit_cast(f16x8, vwf[2 * f + 1]);
      acc[f] = __builtin_amdgcn_mfma_f32_16x16x32_f16(pa0, b0, acc[f], 0, 0, 0);
      acc[f] = __builtin_amdgcn_mfma_f32_16x16x32_f16(pa1, b1, acc[f], 0, 0, 0);
    }
    __builtin_amdgcn_s_setprio(0);

    // --- single sync point per tile ---
    asm volatile("s_waitcnt vmcnt(0)" ::: "memory");
    __syncthreads();
  }

  // ---- epilogue: normalized partial (fp32) + (m, l) stats ----
  if (lhi == 0) {
    float2* st = (float2*)stats;
    st[(size_t)qt * (BB * SS) + (size_t)b * SS + q0 + w * 16 + lrow] =
        make_float2(m_reg, l_reg);
  }
  float rl[4];
  #pragma unroll
  for (int r = 0; r < 4; ++r) rl[r] = 1.0f / __shfl(l_reg, lhi * 4 + r);
  #pragma unroll
  for (int r = 0; r < 4; ++r) {
    size_t base = ((size_t)qt * (BB * SS) + (size_t)b * SS +
                   (size_t)(q0 + w * 16 + lhi * 4 + r)) * 64 + (size_t)lrow;
    #pragma unroll
    for (int f = 0; f < 4; ++f) opart[base + f * 16] = acc[f][r] * rl[r];
  }
}

// ---------------- K4: merge 4 KV-quarters, add bo ----------------
__global__ __launch_bounds__(256) void merge4(
    const float* __restrict__ opart, const float* __restrict__ stats,
    const float* __restrict__ bo, float* __restrict__ out) {
  const int gid = blockIdx.x * 256 + threadIdx.x;
  const int row = gid >> 3;
  const int c8 = (gid & 7) * 8;
  const float2* st = (const float2*)stats;
  float2 sq[4];
  #pragma unroll
  for (int q = 0; q < 4; ++q) sq[q] = st[(size_t)q * (BB * SS) + row];
  float M = fmaxf(fmaxf(sq[0].x, sq[1].x), fmaxf(sq[2].x, sq[3].x));
  float wv[4], Ssum = 0.f;
  #pragma unroll
  for (int q = 0; q < 4; ++q) {
    wv[q] = __expf(sq[q].x - M) * sq[q].y;
    Ssum += wv[q];
  }
  const float inv = 0.35355339059327373f / Ssum;
  #pragma unroll
  for (int q = 0; q < 4; ++q) wv[q] *= inv;

  float o[8];
  #pragma unroll
  for (int j = 0; j < 8; ++j) o[j] = bo[c8 + j];
  #pragma unroll
  for (int q = 0; q < 4; ++q) {
    const float* op = opart + ((size_t)q * (BB * SS) + row) * 64 + c8;
    float4 a = *(const float4*)op;
    float4 bq4 = *(const float4*)(op + 4);
    o[0] += wv[q] * a.x; o[1] += wv[q] * a.y; o[2] += wv[q] * a.z; o[3] += wv[q] * a.w;
    o[4] += wv[q] * bq4.x; o[5] += wv[q] * bq4.y; o[6] += wv[q] * bq4.z; o[7] += wv[q] * bq4.w;
  }
  float* dst = out + (size_t)row * EE + c8;
  *(float4*)dst = make_float4(o[0], o[1], o[2], o[3]);
  *(float4*)(dst + 4) = make_float4(o[4], o[5], o[6], o[7]);
}

extern "C" void kernel_launch(void* const* d_in, const int* in_sizes, int n_in,
                              void* d_out, int out_size, void* d_ws, size_t ws_size,
                              hipStream_t stream) {
  const float* x = (const float*)d_in[0];
  const float* mask = (const float*)d_in[1];
  const float* Wq = (const float*)d_in[2];
  const float* bq = (const float*)d_in[3];
  const float* Wk = (const float*)d_in[4];
  const float* bk = (const float*)d_in[5];  // folded out: row-const cancels in softmax
  const float* Wv = (const float*)d_in[6];
  const float* bv = (const float*)d_in[7];
  const float* Wo = (const float*)d_in[8];
  const float* bo = (const float*)d_in[9];
  float* out = (float*)d_out;
  (void)bk;

  const size_t N64 = (size_t)BB * SS * 64;
  u16* ubuf = (u16*)d_ws;
  u16* xhh = ubuf + N64;
  u16* vwt = xhh + N64;
  float* cbuf = (float*)(vwt + N64);
  float* G = cbuf + (size_t)BB * SS;
  float* g2 = G + 64 * 64;
  float* Wf = g2 + 64;
  float* bf = Wf + 64 * 64;
  float* opart = bf + 64;                        // 4 * BB*SS*64 f32
  float* st = opart + (size_t)4 * BB * SS * 64;  // 4 * BB*SS float2
  unsigned char* flags = (unsigned char*)(st + (size_t)8 * BB * SS);  // 16 KB

  wgfuse<<<130, 256, 0, stream>>>(Wq, bq, Wk, Wv, bv, Wo, G, g2, Wf, bf);
  prep<<<512 + BB * SS / 64, 256, 0, stream>>>(x, G, g2, Wf, bf, mask,
                                               ubuf, xhh, cbuf, vwt, flags);
  attn_fwd<<<512, 512, 34816, stream>>>(ubuf, xhh, vwt, cbuf, mask, flags, opart, st);
  merge4<<<BB * SS * 8 / 256, 256, 0, stream>>>(opart, st, bo, out);
}